// Round 1
// baseline (1674.987 us; speedup 1.0000x reference)
//
#include <hip/hip_runtime.h>
#include <hip/hip_bf16.h>
#include <cmath>

// Problem constants (B=4, H=16, S=2048, D=64)
#define S_LEN 2048
#define D_DIM 64
#define N_BH  64          // B*H
#define TILE  64          // q-tile rows and k-tile cols per block
#define LDW   72          // padded LDS row stride (elements) to break bank conflicts

typedef __attribute__((ext_vector_type(8))) __bf16 bf16x8;
typedef __attribute__((ext_vector_type(4))) float  f32x4;

__device__ __forceinline__ unsigned short f2bf_bits(float x) {
    // round-to-nearest-even fp32 -> bf16 bit pattern (inputs are finite)
    unsigned int u = __float_as_uint(x);
    u += 0x7fffu + ((u >> 16) & 1u);
    return (unsigned short)(u >> 16);
}

// Stage a 64x64 fp32 tile (row stride D_DIM) into LDS as bf16, row-major, stride LDW.
__device__ __forceinline__ void stage_rm(const float* __restrict__ g,
                                         unsigned short* lds, int tid) {
#pragma unroll
    for (int i = 0; i < 4; ++i) {
        int linear = tid + i * 256;            // 0..1023 float4 slots
        int row = linear >> 4;                 // 64 rows
        int col = (linear & 15) << 2;          // 0..60
        const float4 v = *reinterpret_cast<const float4*>(g + row * D_DIM + col);
        ushort4 u;
        u.x = f2bf_bits(v.x); u.y = f2bf_bits(v.y);
        u.z = f2bf_bits(v.z); u.w = f2bf_bits(v.w);
        *reinterpret_cast<ushort4*>(lds + row * LDW + col) = u;
    }
}

// Stage a 64x64 fp32 tile TRANSPOSED into LDS as bf16: lds[d][k] = g[k][d]
__device__ __forceinline__ void stage_tr(const float* __restrict__ g,
                                         unsigned short* lds, int tid) {
#pragma unroll
    for (int i = 0; i < 4; ++i) {
        int linear = tid + i * 256;
        int kk = linear >> 4;
        int d0 = (linear & 15) << 2;
        const float4 v = *reinterpret_cast<const float4*>(g + kk * D_DIM + d0);
        lds[(d0 + 0) * LDW + kk] = f2bf_bits(v.x);
        lds[(d0 + 1) * LDW + kk] = f2bf_bits(v.y);
        lds[(d0 + 2) * LDW + kk] = f2bf_bits(v.z);
        lds[(d0 + 3) * LDW + kk] = f2bf_bits(v.w);
    }
}

__device__ __forceinline__ bf16x8 ldfrag(const unsigned short* lds, int row, int col) {
    return *reinterpret_cast<const bf16x8*>(lds + row * LDW + col);
}

__global__ __launch_bounds__(256) void attn_fused(
        const float* __restrict__ Q, const float* __restrict__ K,
        const float* __restrict__ V, float* __restrict__ out) {
    __shared__ __align__(16) unsigned short q_lds[TILE * LDW];
    __shared__ __align__(16) unsigned short k_lds[TILE * LDW];
    __shared__ __align__(16) unsigned short vT_lds[D_DIM * LDW];
    __shared__ __align__(16) unsigned short w_lds[TILE * LDW];

    const int tid  = threadIdx.x;
    const int bh   = blockIdx.y;
    const int q0   = blockIdx.x * TILE;
    const int wave = tid >> 6;
    const int lane = tid & 63;
    const int quad = lane >> 4;
    const int lr   = lane & 15;
    const int m0   = wave * 16;         // this wave's 16-row strip within the q-tile

    const float* Qg = Q + ((size_t)bh * S_LEN + q0) * D_DIM;
    const float* Kg = K + (size_t)bh * S_LEN * D_DIM;
    const float* Vg = V + (size_t)bh * S_LEN * D_DIM;
    float* out_o = out + ((size_t)bh * S_LEN + q0) * D_DIM;
    float* out_w = out + (size_t)N_BH * S_LEN * D_DIM
                       + ((size_t)bh * S_LEN + q0) * (size_t)S_LEN;

    stage_rm(Qg, q_lds, tid);
    __syncthreads();

    // Q A-fragments are reused across the whole kernel: A[m=lr][k=quad*8+j]
    bf16x8 aq[2];
    aq[0] = ldfrag(q_lds, m0 + lr, quad * 8);
    aq[1] = ldfrag(q_lds, m0 + lr, 32 + quad * 8);

    float m_r[4], l_r[4];
#pragma unroll
    for (int r = 0; r < 4; ++r) { m_r[r] = -INFINITY; l_r[r] = 0.f; }

    // ---------------- Pass A: online softmax stats (m, l) per q-row ----------------
    for (int kb = 0; kb < S_LEN; kb += TILE) {
        __syncthreads();
        stage_rm(Kg + (size_t)kb * D_DIM, k_lds, tid);
        __syncthreads();

        f32x4 acc[4];
#pragma unroll
        for (int nt = 0; nt < 4; ++nt) acc[nt] = f32x4{0.f, 0.f, 0.f, 0.f};
#pragma unroll
        for (int ks = 0; ks < 2; ++ks)
#pragma unroll
            for (int nt = 0; nt < 4; ++nt) {
                bf16x8 b = ldfrag(k_lds, nt * 16 + lr, ks * 32 + quad * 8);
                acc[nt] = __builtin_amdgcn_mfma_f32_16x16x32_bf16(aq[ks], b, acc[nt], 0, 0, 0);
            }

        // C/D layout: row = quad*4 + r, col = nt*16 + lr
        float red[4];
#pragma unroll
        for (int r = 0; r < 4; ++r) {
            float t = fmaxf(fmaxf(acc[0][r], acc[1][r]), fmaxf(acc[2][r], acc[3][r]));
            red[r] = t * 0.125f;
        }
#pragma unroll
        for (int off = 1; off < 16; off <<= 1)
#pragma unroll
            for (int r = 0; r < 4; ++r)
                red[r] = fmaxf(red[r], __shfl_xor(red[r], off, 64));

#pragma unroll
        for (int r = 0; r < 4; ++r) {
            float mn = fmaxf(m_r[r], red[r]);
            float ps = 0.f;
#pragma unroll
            for (int nt = 0; nt < 4; ++nt)
                ps += __expf(acc[nt][r] * 0.125f - mn);
            l_r[r] *= __expf(m_r[r] - mn);
            m_r[r] = mn;
            red[r] = ps;
        }
#pragma unroll
        for (int off = 1; off < 16; off <<= 1)
#pragma unroll
            for (int r = 0; r < 4; ++r)
                red[r] += __shfl_xor(red[r], off, 64);
#pragma unroll
        for (int r = 0; r < 4; ++r) l_r[r] += red[r];
    }

    float rl[4];
#pragma unroll
    for (int r = 0; r < 4; ++r) rl[r] = 1.f / l_r[r];

    f32x4 acco[4];
#pragma unroll
    for (int nt = 0; nt < 4; ++nt) acco[nt] = f32x4{0.f, 0.f, 0.f, 0.f};

    // ------- Pass B: recompute scores, write weights, accumulate O = W @ V -------
    for (int kb = 0; kb < S_LEN; kb += TILE) {
        __syncthreads();   // previous iter's k/vT/w LDS reads are done
        stage_rm(Kg + (size_t)kb * D_DIM, k_lds, tid);
        stage_tr(Vg + (size_t)kb * D_DIM, vT_lds, tid);
        __syncthreads();

        f32x4 acc[4];
#pragma unroll
        for (int nt = 0; nt < 4; ++nt) acc[nt] = f32x4{0.f, 0.f, 0.f, 0.f};
#pragma unroll
        for (int ks = 0; ks < 2; ++ks)
#pragma unroll
            for (int nt = 0; nt < 4; ++nt) {
                bf16x8 b = ldfrag(k_lds, nt * 16 + lr, ks * 32 + quad * 8);
                acc[nt] = __builtin_amdgcn_mfma_f32_16x16x32_bf16(aq[ks], b, acc[nt], 0, 0, 0);
            }

        // weights: w = exp(s - m) / l ; write fp32 to global, bf16 to LDS for PV
#pragma unroll
        for (int nt = 0; nt < 4; ++nt)
#pragma unroll
            for (int r = 0; r < 4; ++r) {
                float w = __expf(acc[nt][r] * 0.125f - m_r[r]) * rl[r];
                out_w[(size_t)(m0 + quad * 4 + r) * S_LEN + kb + nt * 16 + lr] = w;
                w_lds[(m0 + quad * 4 + r) * LDW + nt * 16 + lr] = f2bf_bits(w);
            }
        __syncthreads();   // w_lds ready (also covers vT_lds cross-wave visibility)

        // O += W @ V : A = w_lds rows (this wave's strip), B = vT_lds
#pragma unroll
        for (int ks = 0; ks < 2; ++ks) {
            bf16x8 aw = ldfrag(w_lds, m0 + lr, ks * 32 + quad * 8);
#pragma unroll
            for (int nt = 0; nt < 4; ++nt) {
                bf16x8 b = ldfrag(vT_lds, nt * 16 + lr, ks * 32 + quad * 8);
                acco[nt] = __builtin_amdgcn_mfma_f32_16x16x32_bf16(aw, b, acco[nt], 0, 0, 0);
            }
        }
    }

    // write O (fp32): row = m0 + quad*4 + r, col = nt*16 + lr
#pragma unroll
    for (int nt = 0; nt < 4; ++nt)
#pragma unroll
        for (int r = 0; r < 4; ++r)
            out_o[(size_t)(m0 + quad * 4 + r) * D_DIM + nt * 16 + lr] = acco[nt][r];
}

extern "C" void kernel_launch(void* const* d_in, const int* in_sizes, int n_in,
                              void* d_out, int out_size, void* d_ws, size_t ws_size,
                              hipStream_t stream) {
    (void)in_sizes; (void)n_in; (void)d_ws; (void)ws_size; (void)out_size;
    const float* Q = (const float*)d_in[0];
    const float* K = (const float*)d_in[1];
    const float* V = (const float*)d_in[2];
    float* out = (float*)d_out;
    dim3 grid(S_LEN / TILE, N_BH);   // 32 q-tiles x 64 (b,h)
    attn_fused<<<grid, dim3(256), 0, stream>>>(Q, K, V, out);
}